// Round 15
// baseline (312.552 us; speedup 1.0000x reference)
//
#include <hip/hip_runtime.h>
#include <math.h>

// Problem constants: N=200 LSTMs, B=100, T=256, D=5 (io), H=20 (units)
constexpr int NL = 200;
constexpr int B  = 100;
constexpr int T  = 256;
constexpr int D  = 5;
constexpr int H  = 20;
constexpr int NW    = 7;      // 16-batch groups per LSTM; 7*16=112 >= 100
constexpr int BPAD  = 112;    // padded batch dim of xe (zeros for b>=100)
constexpr int NPAIR = NL / 2; // 100 n-pairs; wave handles (pr, pr+100)

// K=32 bijection (A and B share it positionally, so any bijection is valid):
//   k = 8*g4 + j ; j in 0..4 -> hh = 4*j + g4   (lane-local recurrence)
//   g4=0: j5,j6,j7 = x0,x1,x2 ; g4=1: j5,j6 = x3,x4, j7 = bias(1.0)
//   g4=2,3: j>=5 -> 0
// Lane (g4,c16) C-output rows give gates of hh = 4*Mt + g4 -> same lane owns
// exactly the hh values (hh mod 4 == g4) its next-step B-fragment needs.

typedef float  f32x4  __attribute__((ext_vector_type(4)));
typedef short  bf16x8 __attribute__((ext_vector_type(8)));

__device__ __forceinline__ float rcpf(float x) { return __builtin_amdgcn_rcpf(x); }

#if __has_builtin(__builtin_amdgcn_exp2f)
__device__ __forceinline__ float exp2fast(float x) { return __builtin_amdgcn_exp2f(x); }
#else
__device__ __forceinline__ float exp2fast(float x) { return __expf(x * 0.6931471805599453f); }
#endif

// fp32 -> bf16 bits, round-to-nearest-even
__device__ __forceinline__ unsigned short f2bf(float f) {
    union { float f; unsigned u; } v; v.f = f;
    unsigned r = v.u + 0x7fffu + ((v.u >> 16) & 1u);
    return (unsigned short)(r >> 16);
}
__device__ __forceinline__ unsigned pk2bf(float lo, float hi) {
    return (unsigned)f2bf(lo) | ((unsigned)f2bf(hi) << 16);
}

constexpr float NLOG2E = -1.4426950408889634f;
constexpr float TLOG2E = 2.8853900817779268f;   // 2*log2(e)

__global__ __launch_bounds__(256) void init_out_kernel(const float* __restrict__ dense_b,
                                                       float* __restrict__ out, int n) {
    int i = blockIdx.x * 256 + threadIdx.x;
    if (i < n) out[i] = dense_b[i % D];
}

// xe[g][t][b] (g=0,1): per-lane x/bias fragment pieces ([t][b] order).
//   g=0: {bf16(x0)<<16, pk(x1,x2)}   g=1: {bf16(x3)<<16, pk(x4,1.0)}
__global__ __launch_bounds__(256) void xpack_kernel(const float* __restrict__ x,
                                                    int2* __restrict__ xe) {
    int i = blockIdx.x * 256 + threadIdx.x;
    if (i >= 2 * T * BPAD) return;
    const int g = i / (T * BPAD);
    const int r = i % (T * BPAD);
    const int t = r / BPAD;
    const int b = r % BPAD;
    int2 v = {0, 0};
    if (b < B) {
        const float* s = x + ((size_t)b * T + t) * D;
        if (g == 0) { v.x = (int)((unsigned)f2bf(s[0]) << 16); v.y = (int)pk2bf(s[1], s[2]); }
        else        { v.x = (int)((unsigned)f2bf(s[3]) << 16); v.y = (int)pk2bf(s[4], 1.0f); }
    }
    xe[i] = v;
}

__device__ __forceinline__ float lstm_act(const f32x4 a, float& c) {
    // a = {-z_i, -z_f, 2*z_g, -z_o} * log2e (bias folded into MFMA A)
    const float iv = rcpf(1.0f + exp2fast(a[0]));
    const float fv = rcpf(1.0f + exp2fast(a[1]));
    const float gv = fmaf(-2.0f, rcpf(exp2fast(a[2]) + 1.0f), 1.0f);
    const float ov = rcpf(1.0f + exp2fast(a[3]));
    c = fmaf(fv, c, iv * gv);
    const float th = fmaf(-2.0f, rcpf(exp2fast(TLOG2E * c) + 1.0f), 1.0f);
    return ov * th;
}

// ONE 64-lane wave runs TWO independent LSTMs (n0 = pr, n1 = pr+100) on the
// same 16-batch group w -> the x fragment is loaded once and shared. All
// state in registers, no LDS, no barriers. The two jobs' dependency chains
// interleave in the wave's issue stream: job1's MFMAs/acts fill job0's
// latency stalls and vice versa (the fix for the ~230us wall of R9-R14).
template<bool USE_WS>
__global__ __attribute__((amdgpu_flat_work_group_size(64, 64),
                          amdgpu_waves_per_eu(1, 1)))
void lstm_reg2_kernel(
    const int2*  __restrict__ xe,   // [2][T][BPAD] packed x pieces
    const float* __restrict__ Wg,   // [N][D][4H]
    const float* __restrict__ Ug,   // [N][H][4H]
    const float* __restrict__ bg,   // [N][4H]
    const float* __restrict__ dWg,  // [N*H][D]
    float* __restrict__ pw,         // [N][T][D][B] partials (USE_WS)
    float* __restrict__ out)        // [B][T][D] (atomic fallback)
{
    const int blk = blockIdx.x;            // 0..699
    const int w   = blk % NW;
    const int pr  = blk / NW;
    const int n0  = pr;
    const int n1  = pr + NPAIR;
    const int l   = threadIdx.x;           // 0..63
    const int c16 = l & 15;
    const int g4  = l >> 4;

    const int gateA = c16 & 3;
    const int hA4   = c16 >> 2;
    const float sA  = (gateA == 2) ? TLOG2E : NLOG2E;

    auto buildA = [&](const float* Un, const float* Wn, const float* bn, int Mt) {
        const int colA = gateA * H + (Mt * 4 + hA4);
        bf16x8 a;
        #pragma unroll
        for (int j = 0; j < 8; ++j) {
            float v = 0.0f;
            if (j < 5) {                         // h rows: hh = 4*j + g4
                v = Un[(4 * j + g4) * 4 * H + colA];
            } else if (g4 == 0) {                // x rows 0..2
                v = Wn[(j - 5) * 4 * H + colA];
            } else if (g4 == 1) {                // x rows 3,4 + bias
                v = (j < 7) ? Wn[(j - 2) * 4 * H + colA] : bn[colA];
            }
            a[j] = (short)f2bf(sA * v);
        }
        return a;
    };
    auto buildD = [&](const float* dn) {
        bf16x8 a;
        #pragma unroll
        for (int j = 0; j < 8; ++j) {
            float v = 0.0f;
            if (c16 < D && j < 5) v = dn[(4 * j + g4) * D + c16];
            a[j] = (short)f2bf(v);
        }
        return a;
    };

    const float* Un0 = Ug  + (size_t)n0 * H * 4 * H;
    const float* Wn0 = Wg  + (size_t)n0 * D * 4 * H;
    const float* bn0 = bg  + (size_t)n0 * 4 * H;
    const float* dn0 = dWg + (size_t)n0 * H * D;
    const float* Un1 = Ug  + (size_t)n1 * H * 4 * H;
    const float* Wn1 = Wg  + (size_t)n1 * D * 4 * H;
    const float* bn1 = bg  + (size_t)n1 * 4 * H;
    const float* dn1 = dWg + (size_t)n1 * H * D;

    // 12 A-fragments (48 VGPRs persistent)
    const bf16x8 A00 = buildA(Un0, Wn0, bn0, 0), A01 = buildA(Un0, Wn0, bn0, 1),
                 A02 = buildA(Un0, Wn0, bn0, 2), A03 = buildA(Un0, Wn0, bn0, 3),
                 A04 = buildA(Un0, Wn0, bn0, 4), AD0 = buildD(dn0);
    const bf16x8 A10 = buildA(Un1, Wn1, bn1, 0), A11 = buildA(Un1, Wn1, bn1, 1),
                 A12 = buildA(Un1, Wn1, bn1, 2), A13 = buildA(Un1, Wn1, bn1, 3),
                 A14 = buildA(Un1, Wn1, bn1, 4), AD1 = buildD(dn1);

    const int  bgl    = w * 16 + c16;
    const bool bvalid = bgl < B;
    const int2* xlane = xe + (size_t)(g4 & 1) * T * BPAD + bgl;   // valid for g4<2
    float* pb0 = USE_WS ? (pw + (size_t)n0 * T * (D * B) + bgl)
                        : (out + (size_t)bgl * T * D);
    float* pb1 = USE_WS ? (pw + (size_t)n1 * T * (D * B) + bgl)
                        : (out + (size_t)bgl * T * D);

    int2 xfA = {0, 0}, xfB = {0, 0};
    if (g4 < 2) { xfA = xlane[0]; xfB = xlane[BPAD]; }

    // per-job lane-local state
    float h00 = 0.f, h01 = 0.f, h02 = 0.f, h03 = 0.f, h04 = 0.f;
    float c00 = 0.f, c01 = 0.f, c02 = 0.f, c03 = 0.f, c04 = 0.f;
    float h10 = 0.f, h11 = 0.f, h12 = 0.f, h13 = 0.f, h14 = 0.f;
    float c10 = 0.f, c11 = 0.f, c12 = 0.f, c13 = 0.f, c14 = 0.f;
    const f32x4 z4 = {0.f, 0.f, 0.f, 0.f};
    const float fzero = 0.0f;

    auto pack = [&](float a, float b, float c_, float d, float e, const int2 xf) {
        unsigned w0, w1, w2;
        asm("v_cvt_pk_bf16_f32 %0, %1, %2" : "=v"(w0) : "v"(a), "v"(b));
        asm("v_cvt_pk_bf16_f32 %0, %1, %2" : "=v"(w1) : "v"(c_), "v"(d));
        asm("v_cvt_pk_bf16_f32 %0, %1, %2" : "=v"(w2) : "v"(e), "v"(fzero));
        w2 |= (unsigned)xf.x;
        union { int4 i; bf16x8 v; } ub;
        ub.i = make_int4((int)w0, (int)w1, (int)w2, xf.y);
        return ub.v;
    };
    auto dstore = [&](float* pbase, const f32x4 ad, int t) {
        if (USE_WS) {
            float* pt = pbase + (size_t)t * (D * B);
            if (bvalid && g4 == 0) {
                pt[0 * B] = ad[0]; pt[1 * B] = ad[1];
                pt[2 * B] = ad[2]; pt[3 * B] = ad[3];
            } else if (bvalid && g4 == 1) {
                pt[4 * B] = ad[0];
            }
        } else {
            float* pt = pbase + (size_t)t * D;
            if (bvalid && g4 == 0) {
                atomicAdd(&pt[0], ad[0]); atomicAdd(&pt[1], ad[1]);
                atomicAdd(&pt[2], ad[2]); atomicAdd(&pt[3], ad[3]);
            } else if (bvalid && g4 == 1) {
                atomicAdd(&pt[4], ad[0]);
            }
        }
    };

    auto body = [&](int2& xf, int t) {
        // pack both B fragments: [h(t-1) | x(t) | bias]  (x shared)
        const bf16x8 b0 = pack(h00, h01, h02, h03, h04, xf);
        const bf16x8 b1 = pack(h10, h11, h12, h13, h14, xf);

        // 12 independent MFMAs (two jobs interleave in the MFMA pipe)
        const f32x4 ad0 = __builtin_amdgcn_mfma_f32_16x16x32_bf16(AD0, b0, z4, 0, 0, 0);
        const f32x4 ad1 = __builtin_amdgcn_mfma_f32_16x16x32_bf16(AD1, b1, z4, 0, 0, 0);
        const f32x4 a00 = __builtin_amdgcn_mfma_f32_16x16x32_bf16(A00, b0, z4, 0, 0, 0);
        const f32x4 a10 = __builtin_amdgcn_mfma_f32_16x16x32_bf16(A10, b1, z4, 0, 0, 0);
        const f32x4 a01 = __builtin_amdgcn_mfma_f32_16x16x32_bf16(A01, b0, z4, 0, 0, 0);
        const f32x4 a11 = __builtin_amdgcn_mfma_f32_16x16x32_bf16(A11, b1, z4, 0, 0, 0);
        const f32x4 a02 = __builtin_amdgcn_mfma_f32_16x16x32_bf16(A02, b0, z4, 0, 0, 0);
        const f32x4 a12 = __builtin_amdgcn_mfma_f32_16x16x32_bf16(A12, b1, z4, 0, 0, 0);
        const f32x4 a03 = __builtin_amdgcn_mfma_f32_16x16x32_bf16(A03, b0, z4, 0, 0, 0);
        const f32x4 a13 = __builtin_amdgcn_mfma_f32_16x16x32_bf16(A13, b1, z4, 0, 0, 0);
        const f32x4 a04 = __builtin_amdgcn_mfma_f32_16x16x32_bf16(A04, b0, z4, 0, 0, 0);
        const f32x4 a14 = __builtin_amdgcn_mfma_f32_16x16x32_bf16(A14, b1, z4, 0, 0, 0);

        // prefetch shared x fragment for t+2
        if (g4 < 2) {
            const int tc = (t + 2 < T) ? t + 2 : T - 1;
            xf = xlane[(size_t)tc * BPAD];
        }

        // dense results are for step t-1
        if (t > 0) { dstore(pb0, ad0, t - 1); dstore(pb1, ad1, t - 1); }

        // activations: 10 independent chains -> cross-job ILP
        h00 = lstm_act(a00, c00);  h10 = lstm_act(a10, c10);
        h01 = lstm_act(a01, c01);  h11 = lstm_act(a11, c11);
        h02 = lstm_act(a02, c02);  h12 = lstm_act(a12, c12);
        h03 = lstm_act(a03, c03);  h13 = lstm_act(a13, c13);
        h04 = lstm_act(a04, c04);  h14 = lstm_act(a14, c14);
    };

    for (int t = 0; t < T; t += 2) {
        body(xfA, t);
        body(xfB, t + 1);
    }

    // final dense for h(T-1), both jobs
    {
        const int2 xz = {0, 0};
        const bf16x8 b0 = pack(h00, h01, h02, h03, h04, xz);
        const bf16x8 b1 = pack(h10, h11, h12, h13, h14, xz);
        const f32x4 ad0 = __builtin_amdgcn_mfma_f32_16x16x32_bf16(AD0, b0, z4, 0, 0, 0);
        const f32x4 ad1 = __builtin_amdgcn_mfma_f32_16x16x32_bf16(AD1, b1, z4, 0, 0, 0);
        dstore(pb0, ad0, T - 1);
        dstore(pb1, ad1, T - 1);
    }
}

// out[b][t][d] = dense_b[d] + sum_n pw[n][t][d][b]  (coalesced reads)
__global__ __launch_bounds__(512) void reduce_kernel(
    const float* __restrict__ pw, const float* __restrict__ dense_b,
    float* __restrict__ out)
{
    const int t    = blockIdx.x;
    const int flat = threadIdx.x;              // d*B + b, 0..499
    if (flat >= B * D) return;
    const int d = flat / B;
    const int b = flat % B;
    const float* p = pw + (size_t)t * (D * B) + flat;
    constexpr size_t stride = (size_t)T * D * B;
    float a0 = 0.0f, a1 = 0.0f;
    #pragma unroll 10
    for (int n = 0; n < NL; n += 2) {
        a0 += p[(size_t)n * stride];
        a1 += p[(size_t)(n + 1) * stride];
    }
    out[((size_t)b * T + t) * D + d] = a0 + a1 + dense_b[d];
}

extern "C" void kernel_launch(void* const* d_in, const int* in_sizes, int n_in,
                              void* d_out, int out_size, void* d_ws, size_t ws_size,
                              hipStream_t stream) {
    const float* x   = (const float*)d_in[0];
    const float* Wg  = (const float*)d_in[1];
    const float* Ug  = (const float*)d_in[2];
    const float* bg  = (const float*)d_in[3];
    const float* dWg = (const float*)d_in[4];
    const float* dbv = (const float*)d_in[5];
    float* out = (float*)d_out;

    const size_t xe_bytes = (size_t)2 * T * BPAD * sizeof(int2);      // 458,752
    const size_t pw_bytes = (size_t)NL * T * D * B * sizeof(float);   // 102.4 MB

    int2* xe = (int2*)d_ws;
    xpack_kernel<<<(2 * T * BPAD + 255) / 256, 256, 0, stream>>>(x, xe);

    if (ws_size >= xe_bytes + pw_bytes) {
        float* pw = (float*)((char*)d_ws + xe_bytes);
        lstm_reg2_kernel<true><<<NPAIR * NW, 64, 0, stream>>>(xe, Wg, Ug, bg, dWg, pw, out);
        reduce_kernel<<<T, 512, 0, stream>>>(pw, dbv, out);
    } else {
        init_out_kernel<<<(out_size + 255) / 256, 256, 0, stream>>>(dbv, out, out_size);
        lstm_reg2_kernel<false><<<NPAIR * NW, 64, 0, stream>>>(xe, Wg, Ug, bg, dWg, nullptr, out);
    }
}

// Round 16
// 310.857 us; speedup vs baseline: 1.0055x; 1.0055x over previous
//
#include <hip/hip_runtime.h>
#include <math.h>

// Problem constants: N=200 LSTMs, B=100, T=256, D=5 (io), H=20 (units)
constexpr int NL = 200;
constexpr int B  = 100;
constexpr int T  = 256;
constexpr int D  = 5;
constexpr int H  = 20;
constexpr int NW   = 7;      // 16-batch groups per LSTM; 7*16=112 >= 100
constexpr int BPAD = 112;    // padded batch dim of xe (zeros for b>=100)
constexpr int RP   = 40;     // LDS row pitch in shorts (80 B): banks spread, 16B-aligned

// K=32 bijection (A and B share it positionally, so any bijection is valid):
//   k = 8*g4 + j ; j in 0..4 -> hh = 4*j + g4
//   g4=0: j5,j6,j7 = x0,x1,x2 ; g4=1: j5,j6 = x3,x4, j7 = bias(1.0)
//   g4=2,3: j>=5 -> 0
// Tile Mt output: lane (g4,c16) gets gates of hh = 4*Mt + g4, i.e. j-slot Mt.
// Wave0 computes Mt=0,1 (j-slots 0,1) + dense; wave1 computes Mt=2,3,4
// (j-slots 2,3,4). h exchanged via LDS; x/bias OR'd from registers at read.

typedef float  f32x4  __attribute__((ext_vector_type(4)));
typedef short  bf16x8 __attribute__((ext_vector_type(8)));

#if __has_builtin(__builtin_amdgcn_exp2f)
__device__ __forceinline__ float exp2fast(float x) { return __builtin_amdgcn_exp2f(x); }
#else
__device__ __forceinline__ float exp2fast(float x) { return __expf(x * 0.6931471805599453f); }
#endif

// Reciprocal on the VALU pipe. The measured wall (R9/R12/R14 all ~2050
// cy/step regardless of occupancy 1.37-6.8 w/SIMD) fits a per-CU-shared
// quarter-rate trans unit: 5.47 jobs/CU x 50 trans x 8cy = 2188 cy. Moving
// the 25 rcp/job to VALU Newton halves the trans load. (R13 tried this at
// 1.37 w/SIMD and lost to latency; here 2.7 w/SIMD hides the chains.)
// Seed valid for all normal y; caller keeps y in [1, 2^60].
__device__ __forceinline__ float rcp_nt(float y) {
    float x = __int_as_float(0x7EF311C3 - __float_as_int(y));
    x = x * fmaf(-y, x, 2.0f);
    x = x * fmaf(-y, x, 2.0f);
    return x;
}

// fp32 -> bf16 bits, round-to-nearest-even
__device__ __forceinline__ unsigned short f2bf(float f) {
    union { float f; unsigned u; } v; v.f = f;
    unsigned r = v.u + 0x7fffu + ((v.u >> 16) & 1u);
    return (unsigned short)(r >> 16);
}
__device__ __forceinline__ unsigned pk2bf(float lo, float hi) {
    return (unsigned)f2bf(lo) | ((unsigned)f2bf(hi) << 16);
}

// LDS-only block barrier (dense stores / x prefetch stay in flight)
__device__ __forceinline__ void block_sync_lds() {
    asm volatile("s_waitcnt lgkmcnt(0)" ::: "memory");
    __builtin_amdgcn_s_barrier();
}

constexpr float NLOG2E = -1.4426950408889634f;
constexpr float TLOG2E = 2.8853900817779268f;   // 2*log2(e)

__global__ __launch_bounds__(256) void init_out_kernel(const float* __restrict__ dense_b,
                                                       float* __restrict__ out, int n) {
    int i = blockIdx.x * 256 + threadIdx.x;
    if (i < n) out[i] = dense_b[i % D];
}

// xe[g][t][b] (g=0,1): per-lane x/bias fragment pieces ([t][b] order).
//   g=0: {bf16(x0)<<16, pk(x1,x2)}   g=1: {bf16(x3)<<16, pk(x4,1.0)}
__global__ __launch_bounds__(256) void xpack_kernel(const float* __restrict__ x,
                                                    int2* __restrict__ xe) {
    int i = blockIdx.x * 256 + threadIdx.x;
    if (i >= 2 * T * BPAD) return;
    const int g = i / (T * BPAD);
    const int r = i % (T * BPAD);
    const int t = r / BPAD;
    const int b = r % BPAD;
    int2 v = {0, 0};
    if (b < B) {
        const float* s = x + ((size_t)b * T + t) * D;
        if (g == 0) { v.x = (int)((unsigned)f2bf(s[0]) << 16); v.y = (int)pk2bf(s[1], s[2]); }
        else        { v.x = (int)((unsigned)f2bf(s[3]) << 16); v.y = (int)pk2bf(s[4], 1.0f); }
    }
    xe[i] = v;
}

// Activation chain with trans-minimal form: 5 exp2 (trans pipe) and ZERO
// v_rcp — the 4 gate reciprocals come from 2 pairwise-product Newtons
// (1/(p0*p1) -> 1/p0, 1/p1 via 2 muls), the tanh(c) reciprocal from one
// more Newton. exp2 args clamped at 30 so products stay <= 2^60 (finite,
// Newton-safe); clamping only touches fully-saturated gates (err < 1e-9).
__device__ __forceinline__ float lstm_act(const f32x4 a, float& c) {
    // a = {-z_i, -z_f, 2*z_g, -z_o} * log2e (bias folded into MFMA A)
    const float e0 = exp2fast(fminf(a[0], 30.0f));
    const float e1 = exp2fast(fminf(a[1], 30.0f));
    const float e2 = exp2fast(fminf(a[2], 30.0f));
    const float e3 = exp2fast(fminf(a[3], 30.0f));
    const float p0 = 1.0f + e0, p1 = 1.0f + e1;
    const float p2 = e2 + 1.0f, p3 = 1.0f + e3;
    const float r01 = rcp_nt(p0 * p1);
    const float r23 = rcp_nt(p2 * p3);
    const float iv = r01 * p1;                      // sigmoid(z_i) = 1/p0
    const float fv = r01 * p0;                      // sigmoid(z_f) = 1/p1
    const float gv = fmaf(-2.0f, r23 * p3, 1.0f);   // tanh(z_g) = 1 - 2/p2
    const float ov = r23 * p2;                      // sigmoid(z_o) = 1/p3
    c = fmaf(fv, c, iv * gv);
    const float et = exp2fast(fminf(TLOG2E * c, 30.0f));
    const float th = fmaf(-2.0f, rcp_nt(et + 1.0f), 1.0f);
    return ov * th;
}

// One block = 2 waves per (lstm n, 16-batch group w). Wave0: gate tiles
// Mt=0,1 + dense MFMA + dense stores + acts for j-slots 0,1. Wave1: gate
// tiles Mt=2,3,4 + acts for j-slots 2,3,4. h state double-buffered in LDS
// (b128 read; b32/b16 writes); x/bias OR'd from registers after the read.
// ONE lgkm-only barrier per step.
template<bool USE_WS>
__global__ __attribute__((amdgpu_flat_work_group_size(128, 128),
                          amdgpu_waves_per_eu(1, 4)))
void lstm2w_kernel(
    const int2*  __restrict__ xe,   // [2][T][BPAD] packed x pieces
    const float* __restrict__ Wg,   // [N][D][4H]
    const float* __restrict__ Ug,   // [N][H][4H]
    const float* __restrict__ bg,   // [N][4H]
    const float* __restrict__ dWg,  // [N*H][D]
    float* __restrict__ pw,         // [N][T][D][B] partials (USE_WS)
    float* __restrict__ out)        // [B][T][D] (atomic fallback)
{
    const int blk = blockIdx.x;            // 0..1399
    const int n   = blk / NW;
    const int w   = blk % NW;
    const int tid = threadIdx.x;
    const int wid = tid >> 6;              // 0 or 1
    const int l   = tid & 63;
    const int c16 = l & 15;
    const int g4  = l >> 4;

    __shared__ __align__(16) short hbuf[2][16][RP];   // 2.5 KB, h region only

    for (int i = tid; i < 2 * 16 * RP / 2; i += 128)
        ((int*)&hbuf[0][0][0])[i] = 0;

    const float* Un = Ug  + (size_t)n * H * 4 * H;
    const float* Wn = Wg  + (size_t)n * D * 4 * H;
    const float* bn = bg  + (size_t)n * 4 * H;
    const float* dn = dWg + (size_t)n * H * D;

    // ---- A fragments, element j <-> k = 8*g4 + j (round-12 bijection) ----
    const int gateA = c16 & 3;
    const int hA4   = c16 >> 2;
    const float sA  = (gateA == 2) ? TLOG2E : NLOG2E;
    auto build = [&](int Mt) {
        const int colA = gateA * H + (Mt * 4 + hA4);
        bf16x8 a;
        #pragma unroll
        for (int j = 0; j < 8; ++j) {
            float v = 0.0f;
            if (j < 5) {                         // h rows: hh = 4*j + g4
                v = Un[(4 * j + g4) * 4 * H + colA];
            } else if (g4 == 0) {                // x rows 0..2
                v = Wn[(j - 5) * 4 * H + colA];
            } else if (g4 == 1) {                // x rows 3,4 + bias
                v = (j < 7) ? Wn[(j - 2) * 4 * H + colA] : bn[colA];
            }
            a[j] = (short)f2bf(sA * v);
        }
        return a;
    };
    bf16x8 afX, afY, afZ;
    if (wid == 0) {
        afX = build(0); afY = build(1);
        // dense A: rows c16<5 = d, h rows only
        #pragma unroll
        for (int j = 0; j < 8; ++j) {
            float v = 0.0f;
            if (c16 < D && j < 5) v = dn[(4 * j + g4) * D + c16];
            afZ[j] = (short)f2bf(v);
        }
    } else {
        afX = build(2); afY = build(3); afZ = build(4);
    }

    const int  bgl    = w * 16 + c16;
    const bool bvalid = bgl < B;
    const int2* xlane = xe + (size_t)(g4 & 1) * T * BPAD + bgl;   // valid for g4<2
    float* pbase = USE_WS ? (pw + (size_t)n * T * (D * B) + bgl)
                          : (out + (size_t)bgl * T * D);

    char* lb = (char*)&hbuf[0][0][0];
    const int rdo  = c16 * (RP * 2) + g4 * 16;     // 16B-aligned b128 read
    const int wo01 = rdo;                          // wave0 b32 (j=0,1)
    const int wo23 = rdo + 4;                      // wave1 b32 (j=2,3)
    const int wo4  = rdo + 8;                      // wave1 b16 (j=4)
    constexpr int BUF = 16 * RP * 2;               // bytes per buffer

    __syncthreads();                               // zero-init visible

    int2 xfA = {0, 0}, xfB = {0, 0};
    if (g4 < 2) { xfA = xlane[0]; xfB = xlane[BPAD]; }

    float cA = 0.f, cB = 0.f, cC = 0.f;
    const f32x4 z4 = {0.f, 0.f, 0.f, 0.f};
    const float fzero = 0.0f;

    auto body = [&](int2& xf, int t, int p) {
        // B fragment: h(t-1) from LDS, x(t)/bias OR'd from registers
        int4 hv = *(const int4*)(lb + p * BUF + rdo);
        hv.z |= xf.x;                              // j5 (hi short)
        hv.w |= xf.y;                              // j6,j7
        union { int4 i; bf16x8 v; } ub; ub.i = hv;
        const bf16x8 bfrag = ub.v;

        const f32x4 aX = __builtin_amdgcn_mfma_f32_16x16x32_bf16(afX, bfrag, z4, 0, 0, 0);
        const f32x4 aY = __builtin_amdgcn_mfma_f32_16x16x32_bf16(afY, bfrag, z4, 0, 0, 0);
        const f32x4 aZ = __builtin_amdgcn_mfma_f32_16x16x32_bf16(afZ, bfrag, z4, 0, 0, 0);

        // prefetch x fragment for t+2
        if (g4 < 2) {
            const int tc = (t + 2 < T) ? t + 2 : T - 1;
            xf = xlane[(size_t)tc * BPAD];
        }

        if (wid == 0) {
            // dense result (aZ) is for step t-1
            if (t > 0) {
                if (USE_WS) {
                    float* pt = pbase + (size_t)(t - 1) * (D * B);
                    if (bvalid && g4 == 0) {
                        pt[0 * B] = aZ[0]; pt[1 * B] = aZ[1];
                        pt[2 * B] = aZ[2]; pt[3 * B] = aZ[3];
                    } else if (bvalid && g4 == 1) {
                        pt[4 * B] = aZ[0];
                    }
                } else {
                    float* pt = pbase + (size_t)(t - 1) * D;
                    if (bvalid && g4 == 0) {
                        atomicAdd(&pt[0], aZ[0]); atomicAdd(&pt[1], aZ[1]);
                        atomicAdd(&pt[2], aZ[2]); atomicAdd(&pt[3], aZ[3]);
                    } else if (bvalid && g4 == 1) {
                        atomicAdd(&pt[4], aZ[0]);
                    }
                }
            }
            const float h0 = lstm_act(aX, cA);
            const float h1 = lstm_act(aY, cB);
            unsigned w0;
            asm("v_cvt_pk_bf16_f32 %0, %1, %2" : "=v"(w0) : "v"(h0), "v"(h1));
            *(unsigned*)(lb + (p ^ 1) * BUF + wo01) = w0;
        } else {
            const float h2 = lstm_act(aX, cA);
            const float h3 = lstm_act(aY, cB);
            const float h4 = lstm_act(aZ, cC);
            unsigned w0, w1;
            asm("v_cvt_pk_bf16_f32 %0, %1, %2" : "=v"(w0) : "v"(h2), "v"(h3));
            asm("v_cvt_pk_bf16_f32 %0, %1, %2" : "=v"(w1) : "v"(h4), "v"(fzero));
            *(unsigned*)(lb + (p ^ 1) * BUF + wo23) = w0;
            *(short*)(lb + (p ^ 1) * BUF + wo4) = (short)w1;
        }
        block_sync_lds();                          // h(t) visible for step t+1
    };

    for (int t = 0; t < T; t += 2) {
        body(xfA, t, 0);
        body(xfB, t + 1, 1);
    }

    // final dense for h(T-1): sits in buffer 0 (T even); x rows of afd are zero
    if (wid == 0) {
        union { int4 i; bf16x8 v; } ub;
        ub.i = *(const int4*)(lb + rdo);
        const f32x4 aZ = __builtin_amdgcn_mfma_f32_16x16x32_bf16(afZ, ub.v, z4, 0, 0, 0);
        if (USE_WS) {
            float* pt = pbase + (size_t)(T - 1) * (D * B);
            if (bvalid && g4 == 0) {
                pt[0 * B] = aZ[0]; pt[1 * B] = aZ[1];
                pt[2 * B] = aZ[2]; pt[3 * B] = aZ[3];
            } else if (bvalid && g4 == 1) {
                pt[4 * B] = aZ[0];
            }
        } else {
            float* pt = pbase + (size_t)(T - 1) * D;
            if (bvalid && g4 == 0) {
                atomicAdd(&pt[0], aZ[0]); atomicAdd(&pt[1], aZ[1]);
                atomicAdd(&pt[2], aZ[2]); atomicAdd(&pt[3], aZ[3]);
            } else if (bvalid && g4 == 1) {
                atomicAdd(&pt[4], aZ[0]);
            }
        }
    }
}

// out[b][t][d] = dense_b[d] + sum_n pw[n][t][d][b]  (coalesced reads)
__global__ __launch_bounds__(512) void reduce_kernel(
    const float* __restrict__ pw, const float* __restrict__ dense_b,
    float* __restrict__ out)
{
    const int t    = blockIdx.x;
    const int flat = threadIdx.x;              // d*B + b, 0..499
    if (flat >= B * D) return;
    const int d = flat / B;
    const int b = flat % B;
    const float* p = pw + (size_t)t * (D * B) + flat;
    constexpr size_t stride = (size_t)T * D * B;
    float a0 = 0.0f, a1 = 0.0f;
    #pragma unroll 10
    for (int n = 0; n < NL; n += 2) {
        a0 += p[(size_t)n * stride];
        a1 += p[(size_t)(n + 1) * stride];
    }
    out[((size_t)b * T + t) * D + d] = a0 + a1 + dense_b[d];
}

extern "C" void kernel_launch(void* const* d_in, const int* in_sizes, int n_in,
                              void* d_out, int out_size, void* d_ws, size_t ws_size,
                              hipStream_t stream) {
    const float* x   = (const float*)d_in[0];
    const float* Wg  = (const float*)d_in[1];
    const float* Ug  = (const float*)d_in[2];
    const float* bg  = (const float*)d_in[3];
    const float* dWg = (const float*)d_in[4];
    const float* dbv = (const float*)d_in[5];
    float* out = (float*)d_out;

    const size_t xe_bytes = (size_t)2 * T * BPAD * sizeof(int2);      // 458,752
    const size_t pw_bytes = (size_t)NL * T * D * B * sizeof(float);   // 102.4 MB

    int2* xe = (int2*)d_ws;
    xpack_kernel<<<(2 * T * BPAD + 255) / 256, 256, 0, stream>>>(x, xe);

    if (ws_size >= xe_bytes + pw_bytes) {
        float* pw = (float*)((char*)d_ws + xe_bytes);
        lstm2w_kernel<true><<<NL * NW, 128, 0, stream>>>(xe, Wg, Ug, bg, dWg, pw, out);
        reduce_kernel<<<T, 512, 0, stream>>>(pw, dbv, out);
    } else {
        init_out_kernel<<<(out_size + 255) / 256, 256, 0, stream>>>(dbv, out, out_size);
        lstm2w_kernel<false><<<NL * NW, 128, 0, stream>>>(xe, Wg, Ug, bg, dWg, nullptr, out);
    }
}